// Round 1
// baseline (51242.889 us; speedup 1.0000x reference)
//
#include <hip/hip_runtime.h>
#include <math.h>

// LSTM_11089605558768: T=16384 sequential steps, H=512, IN=32, OUT=1 (only last
// prediction needed -> only final h matters).
//
// Design: persistent-grid scan. 32 workgroups x 256 threads; each workgroup owns
// 16 h-elements (64 gate rows). The 64x544 weight slice ([W_hh | W_ih] folded)
// lives in VGPRs (136 floats/thread). Per step:
//   poll 32 step-flags (agent scope) -> gather h (+x_t) into LDS -> register FMA
//   -> cross-wave LDS reduction -> activations (wave 0) -> store h slice + flag.
// Double-buffered global h in d_ws; flags are monotone step counters, release
// stores / relaxed polls (agent scope = correct across non-coherent XCD L2s).

#define T_STEPS 16384
#define IN_DIM  32
#define H_DIM   512
#define KWG     32      // workgroups (each owns H_DIM/KWG h elements)
#define H_SLICE 16      // H_DIM / KWG
#define KTOT    544     // H_DIM + IN_DIM (folded input contribution)
#define CHUNK   136     // KTOT / 4 waves

__device__ __forceinline__ float sigmoidf_(float v) {
  return 1.0f / (1.0f + expf(-v));
}

__launch_bounds__(256, 1)
__global__ void lstm_scan_kernel(
    const float* __restrict__ x,     // [T, 32]
    const float* __restrict__ Wih,   // [2048, 32]
    const float* __restrict__ Whh,   // [2048, 512]
    const float* __restrict__ bih,   // [2048]
    const float* __restrict__ bhh,   // [2048]
    const float* __restrict__ Wlin,  // [512] (OUT=1)
    const float* __restrict__ blin,  // [1]
    float* __restrict__ out,         // [1]
    float* hglob,                    // [2][512] double-buffered h (in d_ws)
    unsigned int* flags)             // [32] per-wg completed-step counters
{
  const int wg  = blockIdx.x;
  const int tid = threadIdx.x;
  const int w   = tid >> 6;   // wave 0..3 -> k-chunk
  const int l   = tid & 63;   // lane -> local gate row

  __shared__ __align__(16) float hshm[KTOT];  // [0,512)=h, [512,544)=x_t
  __shared__ float red[256];                  // per-wave partials

  // local row l: 0..15 = i-gates, 16..31 = f, 32..47 = g, 48..63 = o
  const int R = (l >> 4) * H_DIM + wg * H_SLICE + (l & 15);  // global gate row

  // Load persistent weight slice into registers: wreg[j] = W'[R][w*136 + j]
  // where W' = [W_hh | W_ih] (one-time, latency irrelevant).
  float wreg[CHUNK];
  #pragma unroll
  for (int j = 0; j < CHUNK; ++j) {
    const int k = w * CHUNK + j;
    const float* src;
    int idx;
    if (k < H_DIM) { src = Whh; idx = R * H_DIM + k; }
    else           { src = Wih; idx = R * IN_DIM + (k - H_DIM); }
    wreg[j] = src[idx];
  }

  float bias = 0.0f;
  if (w == 0) bias = bih[R] + bhh[R];

  float c = 0.0f;  // cell state, lanes 0..15 of wave 0 (h index wg*16 + l)

  for (int t = 0; t < T_STEPS; ++t) {
    // x_t prefetch: issue before the poll (flag-independent)
    float xv = 0.0f;
    if (tid < IN_DIM) xv = x[t * IN_DIM + tid];

    // ---- wait until all workgroups have produced h(t) ----
    if (w == 0) {
      const unsigned int tgt = (unsigned int)t;
      const int fi = l & 31;
      while (true) {
        unsigned int v = __hip_atomic_load(&flags[fi], __ATOMIC_RELAXED,
                                           __HIP_MEMORY_SCOPE_AGENT);
        if (__all((int)(v >= tgt))) break;
      }
      __builtin_amdgcn_fence(__ATOMIC_ACQUIRE, "agent");
    }
    __syncthreads();  // barrier A

    // ---- gather h(t) (+ x_t) into LDS ----
    {
      const float* hsrc = hglob + (t & 1) * H_DIM;
      const int i0 = tid * 2;
      hshm[i0] = __hip_atomic_load(hsrc + i0, __ATOMIC_RELAXED,
                                   __HIP_MEMORY_SCOPE_AGENT);
      hshm[i0 + 1] = __hip_atomic_load(hsrc + i0 + 1, __ATOMIC_RELAXED,
                                       __HIP_MEMORY_SCOPE_AGENT);
      if (tid < IN_DIM) hshm[H_DIM + tid] = xv;
    }
    __syncthreads();  // barrier B

    // ---- matvec: thread (w,l) covers row l, k in [w*136, w*136+136) ----
    const float4* hv = (const float4*)(hshm + w * CHUNK);  // 544B-aligned chunk
    float a0 = 0.f, a1 = 0.f, a2 = 0.f, a3 = 0.f;
    #pragma unroll
    for (int q = 0; q < CHUNK / 4; ++q) {
      const float4 h4 = hv[q];  // wave-uniform broadcast read
      a0 = fmaf(wreg[4 * q + 0], h4.x, a0);
      a1 = fmaf(wreg[4 * q + 1], h4.y, a1);
      a2 = fmaf(wreg[4 * q + 2], h4.z, a2);
      a3 = fmaf(wreg[4 * q + 3], h4.w, a3);
    }
    red[w * 64 + l] = (a0 + a1) + (a2 + a3);
    __syncthreads();  // barrier C

    // ---- wave 0: finalize gates, update c/h, publish ----
    if (w == 0) {
      const float g = bias + red[l] + red[64 + l] + red[128 + l] + red[192 + l];
      const int j = l & 15;
      const float gi = __shfl(g, j, 64);
      const float gf = __shfl(g, j + 16, 64);
      const float gg = __shfl(g, j + 32, 64);
      const float go = __shfl(g, j + 48, 64);
      if (l < H_SLICE) {
        const float ig = sigmoidf_(gi);
        const float fg = sigmoidf_(gf);
        const float gt = tanhf(gg);
        const float og = sigmoidf_(go);
        c = fg * c + ig * gt;
        const float h = og * tanhf(c);
        __hip_atomic_store(hglob + ((t + 1) & 1) * H_DIM + wg * H_SLICE + l, h,
                           __ATOMIC_RELAXED, __HIP_MEMORY_SCOPE_AGENT);
      }
      if (l == 0) {
        __hip_atomic_store(&flags[wg], (unsigned int)(t + 1),
                           __ATOMIC_RELEASE, __HIP_MEMORY_SCOPE_AGENT);
      }
    }
  }

  // ---- wg 0: final projection out = h(T) . Wlin + blin ----
  if (wg == 0) {
    if (w == 0) {
      while (true) {
        unsigned int v = __hip_atomic_load(&flags[l & 31], __ATOMIC_RELAXED,
                                           __HIP_MEMORY_SCOPE_AGENT);
        if (__all((int)(v >= (unsigned int)T_STEPS))) break;
      }
      __builtin_amdgcn_fence(__ATOMIC_ACQUIRE, "agent");
    }
    __syncthreads();
    {
      const float* hsrc = hglob + (T_STEPS & 1) * H_DIM;
      const int i0 = tid * 2;
      hshm[i0] = __hip_atomic_load(hsrc + i0, __ATOMIC_RELAXED,
                                   __HIP_MEMORY_SCOPE_AGENT);
      hshm[i0 + 1] = __hip_atomic_load(hsrc + i0 + 1, __ATOMIC_RELAXED,
                                       __HIP_MEMORY_SCOPE_AGENT);
    }
    __syncthreads();
    if (w == 0) {
      float p = 0.0f;
      #pragma unroll
      for (int m = 0; m < 8; ++m)
        p = fmaf(hshm[l * 8 + m], Wlin[l * 8 + m], p);
      #pragma unroll
      for (int off = 32; off > 0; off >>= 1) p += __shfl_down(p, off, 64);
      if (l == 0) out[0] = p + blin[0];
    }
  }
}

extern "C" void kernel_launch(void* const* d_in, const int* in_sizes, int n_in,
                              void* d_out, int out_size, void* d_ws, size_t ws_size,
                              hipStream_t stream) {
  const float* x    = (const float*)d_in[0];
  const float* Wih  = (const float*)d_in[1];
  const float* Whh  = (const float*)d_in[2];
  const float* bih  = (const float*)d_in[3];
  const float* bhh  = (const float*)d_in[4];
  const float* Wlin = (const float*)d_in[5];
  const float* blin = (const float*)d_in[6];
  float* out = (float*)d_out;

  float* hglob = (float*)d_ws;                              // 2*512 floats
  unsigned int* flags = (unsigned int*)((char*)d_ws + 4096); // 32 u32

  // d_ws is poisoned 0xAA before every timed call: zero h(0) and flags first.
  hipMemsetAsync(d_ws, 0, 8192, stream);
  hipLaunchKernelGGL(lstm_scan_kernel, dim3(KWG), dim3(256), 0, stream,
                     x, Wih, Whh, bih, bhh, Wlin, blin, out, hglob, flags);
}

// Round 2
// 31921.750 us; speedup vs baseline: 1.6053x; 1.6053x over previous
//
#include <hip/hip_runtime.h>
#include <math.h>

// LSTM_11089605558768: T=16384 sequential steps, H=512, IN=32, OUT=1.
// Persistent-grid scan, 32 wgs x 256 threads, weights resident in VGPRs
// (136 floats/thread = 64x544 slice per wg, [W_hh | W_ih] folded).
//
// R1 change: cross-wg h exchange via SELF-VALIDATING 8B packets
// (u64 = tag<<32 | float bits), relaxed agent-scope atomics. One dependent
// load both detects readiness and delivers the value -> 1 LLC round trip
// instead of flag-poll + fence + re-read (~3 trips). Parity double-buffer;
// 2-slot argument guarantees no overwrite-before-read. Zeroed buffer
// encodes (tag=0, h=0) = the initial state for free.

#define T_STEPS 16384
#define IN_DIM  32
#define H_DIM   512
#define KWG     32      // workgroups; each owns H_DIM/KWG h elements
#define H_SLICE 16      // H_DIM / KWG
#define KTOT    544     // H_DIM + IN_DIM
#define CHUNK   136     // KTOT / 4 waves

__device__ __forceinline__ float fast_sigmoid(float v) {
  return 1.0f / (1.0f + __expf(-v));
}
__device__ __forceinline__ float fast_tanh(float v) {
  return 2.0f / (1.0f + __expf(-2.0f * v)) - 1.0f;   // 2*sigmoid(2x)-1
}

__launch_bounds__(256, 1)
__global__ void lstm_scan_kernel(
    const float* __restrict__ x,     // [T, 32]
    const float* __restrict__ Wih,   // [2048, 32]
    const float* __restrict__ Whh,   // [2048, 512]
    const float* __restrict__ bih,   // [2048]
    const float* __restrict__ bhh,   // [2048]
    const float* __restrict__ Wlin,  // [512]
    const float* __restrict__ blin,  // [1]
    float* __restrict__ out,         // [1]
    unsigned long long* pub)         // [2][512] (tag,val) packets, in d_ws
{
  const int wg  = blockIdx.x;
  const int tid = threadIdx.x;
  const int w   = tid >> 6;   // wave 0..3 -> k-chunk
  const int l   = tid & 63;   // lane -> local gate row

  __shared__ __align__(16) float hshm[KTOT];  // [0,512)=h(t), [512,544)=x_t
  __shared__ float red[256];                  // per-wave partials

  // local row l: 0..15 = i, 16..31 = f, 32..47 = g, 48..63 = o
  const int R = (l >> 4) * H_DIM + wg * H_SLICE + (l & 15);

  // Persistent weight slice -> registers (one-time).
  float wreg[CHUNK];
  #pragma unroll
  for (int j = 0; j < CHUNK; ++j) {
    const int k = w * CHUNK + j;
    wreg[j] = (k < H_DIM) ? Whh[R * H_DIM + k]
                          : Wih[R * IN_DIM + (k - H_DIM)];
  }
  const float bias = (w == 0) ? (bih[R] + bhh[R]) : 0.0f;

  float c = 0.0f;  // cell state: wave 0, lanes 0..15 (h index wg*16 + l)

  // Each thread gathers 2 h elements per step; own-wg elements bypass global.
  const int  e0 = tid * 2, e1 = tid * 2 + 1;
  const bool own0 = (e0 >> 4) == wg, own1 = (e1 >> 4) == wg;
  if (own0) hshm[e0] = 0.0f;   // h(0) = 0 for the own-slice LDS shortcut
  if (own1) hshm[e1] = 0.0f;

  for (int t = 0; t < T_STEPS; ++t) {
    // x_t load (flag-independent, overlaps with poll)
    float xv = (tid < IN_DIM) ? x[t * IN_DIM + tid] : 0.0f;

    // ---- gather h(t): poll self-validating packets (tag == t) ----
    {
      const unsigned long long* p = pub + (t & 1) * H_DIM;
      const unsigned int tg = (unsigned int)t;
      bool need0 = !own0, need1 = !own1;
      while (need0 | need1) {
        if (need0) {
          unsigned long long u = __hip_atomic_load(p + e0, __ATOMIC_RELAXED,
                                                   __HIP_MEMORY_SCOPE_AGENT);
          if ((unsigned int)(u >> 32) == tg) {
            hshm[e0] = __uint_as_float((unsigned int)u);
            need0 = false;
          }
        }
        if (need1) {
          unsigned long long u = __hip_atomic_load(p + e1, __ATOMIC_RELAXED,
                                                   __HIP_MEMORY_SCOPE_AGENT);
          if ((unsigned int)(u >> 32) == tg) {
            hshm[e1] = __uint_as_float((unsigned int)u);
            need1 = false;
          }
        }
      }
      if (tid < IN_DIM) hshm[H_DIM + tid] = xv;
    }
    __syncthreads();  // barrier B: h(t) + x_t staged

    // ---- matvec: thread (w,l) covers row l, k in [w*136, w*136+136) ----
    const float4* hv = (const float4*)(hshm + w * CHUNK);  // 544B-aligned
    float a0 = 0.f, a1 = 0.f, a2 = 0.f, a3 = 0.f;
    #pragma unroll
    for (int q = 0; q < CHUNK / 4; ++q) {
      const float4 h4 = hv[q];  // wave-uniform broadcast read
      a0 = fmaf(wreg[4 * q + 0], h4.x, a0);
      a1 = fmaf(wreg[4 * q + 1], h4.y, a1);
      a2 = fmaf(wreg[4 * q + 2], h4.z, a2);
      a3 = fmaf(wreg[4 * q + 3], h4.w, a3);
    }
    red[w * 64 + l] = (a0 + a1) + (a2 + a3);
    __syncthreads();  // barrier C: partials ready

    // ---- wave 0: finalize gates, update c/h, publish ----
    if (w == 0) {
      const float g = bias + red[l] + red[64 + l] + red[128 + l] + red[192 + l];
      const int j = l & 15;
      const float gi = __shfl(g, j, 64);
      const float gf = __shfl(g, j + 16, 64);
      const float gg = __shfl(g, j + 32, 64);
      const float go = __shfl(g, j + 48, 64);
      if (l < H_SLICE) {
        const float ig = fast_sigmoid(gi);
        const float fg = fast_sigmoid(gf);
        const float gt = fast_tanh(gg);
        const float og = fast_sigmoid(go);
        c = fg * c + ig * gt;
        const float h = og * fast_tanh(c);
        hshm[wg * H_SLICE + l] = h;  // own-slice shortcut for step t+1
        const unsigned long long u =
            ((unsigned long long)(unsigned int)(t + 1) << 32) |
            (unsigned long long)__float_as_uint(h);
        __hip_atomic_store(pub + ((t + 1) & 1) * H_DIM + wg * H_SLICE + l, u,
                           __ATOMIC_RELAXED, __HIP_MEMORY_SCOPE_AGENT);
      }
    }
    // no barrier needed here: hshm[own] / red hazards covered by B/C (disjoint
    // index sets; wave 1-3 can't write red(t+1) before wave 0 passes B(t+1)).
  }

  // ---- wg 0: final projection out = h(T) . Wlin + blin ----
  if (wg == 0) {
    const unsigned long long* p = pub + (T_STEPS & 1) * H_DIM;
    const unsigned int tg = (unsigned int)T_STEPS;
    bool need0 = !own0, need1 = !own1;  // own slice already in hshm
    while (need0 | need1) {
      if (need0) {
        unsigned long long u = __hip_atomic_load(p + e0, __ATOMIC_RELAXED,
                                                 __HIP_MEMORY_SCOPE_AGENT);
        if ((unsigned int)(u >> 32) == tg) {
          hshm[e0] = __uint_as_float((unsigned int)u);
          need0 = false;
        }
      }
      if (need1) {
        unsigned long long u = __hip_atomic_load(p + e1, __ATOMIC_RELAXED,
                                                 __HIP_MEMORY_SCOPE_AGENT);
        if ((unsigned int)(u >> 32) == tg) {
          hshm[e1] = __uint_as_float((unsigned int)u);
          need1 = false;
        }
      }
    }
    __syncthreads();
    red[tid] = hshm[e0] * Wlin[e0] + hshm[e1] * Wlin[e1];
    __syncthreads();
    if (w == 0) {
      float s = red[l] + red[64 + l] + red[128 + l] + red[192 + l];
      #pragma unroll
      for (int off = 32; off > 0; off >>= 1) s += __shfl_down(s, off, 64);
      if (l == 0) out[0] = s + blin[0];
    }
  }
}

extern "C" void kernel_launch(void* const* d_in, const int* in_sizes, int n_in,
                              void* d_out, int out_size, void* d_ws, size_t ws_size,
                              hipStream_t stream) {
  const float* x    = (const float*)d_in[0];
  const float* Wih  = (const float*)d_in[1];
  const float* Whh  = (const float*)d_in[2];
  const float* bih  = (const float*)d_in[3];
  const float* bhh  = (const float*)d_in[4];
  const float* Wlin = (const float*)d_in[5];
  const float* blin = (const float*)d_in[6];
  float* out = (float*)d_out;

  unsigned long long* pub = (unsigned long long*)d_ws;  // [2][512] u64 = 8KB

  // d_ws is re-poisoned 0xAA before every timed call; zeroed pub encodes
  // (tag=0, h=0) == the initial hidden state.
  hipMemsetAsync(d_ws, 0, 8192, stream);
  hipLaunchKernelGGL(lstm_scan_kernel, dim3(KWG), dim3(256), 0, stream,
                     x, Wih, Whh, bih, bhh, Wlin, blin, out, pub);
}